// Round 1
// baseline (3583.193 us; speedup 1.0000x reference)
//
#include <hip/hip_runtime.h>
#include <math.h>

// Problem constants
#define BSZ   32768
#define FDIM  256
#define HDIM  128
#define OUTD  64
#define SQRT_HALF 0.70710678118654752f
#define BN_EPS 1e-5f
#define SM_EPS 1e-5f
#define INV_B (1.0f / 32768.0f)

// ---------------- wave / block reduce helpers ----------------
__device__ inline float waveMax(float v) {
#pragma unroll
    for (int o = 32; o > 0; o >>= 1) v = fmaxf(v, __shfl_down(v, o, 64));
    return v;
}
__device__ inline float waveSum(float v) {
#pragma unroll
    for (int o = 32; o > 0; o >>= 1) v += __shfl_down(v, o, 64);
    return v;
}

// ---------------- column stats for x (B x 256) ----------------
__global__ __launch_bounds__(256) void colstats(const float* __restrict__ X,
                                                float* __restrict__ stats) {
    const int c = threadIdx.x;
    float s = 0.f, q = 0.f;
    for (int r = blockIdx.x; r < BSZ; r += gridDim.x) {
        float v = X[(size_t)r * FDIM + c];
        s += v; q += v * v;
    }
    atomicAdd(&stats[c], s);
    atomicAdd(&stats[FDIM + c], q);
}

// ---------------- normalize x, write out=5*relu(x_bn[:, :64]), init compl ----------------
__global__ __launch_bounds__(256) void norm_x(const float* __restrict__ x,
                                              const float* __restrict__ stats,
                                              const float* __restrict__ g,
                                              const float* __restrict__ b,
                                              float* __restrict__ x_bn,
                                              float* __restrict__ cmpl,
                                              float* __restrict__ out) {
    const int idx = blockIdx.x * 256 + threadIdx.x;   // 0 .. B*256
    const int row = idx >> 8, c = idx & 255;
    float mean = stats[c] * INV_B;
    float var  = stats[FDIM + c] * INV_B - mean * mean;
    float sc   = g[c] * rsqrtf(var + BN_EPS);
    float sh   = b[c] - mean * sc;
    float n = x[idx] * sc + sh;
    x_bn[idx] = n;
    cmpl[idx] = 1.0f;
    if (c < OUTD) out[(size_t)row * OUTD + c] = 5.0f * fmaxf(n, 0.0f);
}

// ---------------- tiled fp32 GEMM with fused column stats ----------------
// C(B x 256) = A(B x K) @ W(K x 256); also accumulates per-column sum/sumsq into stats[512].
// A accessed as A[row*lda + koff + k].
__global__ __launch_bounds__(256) void gemm_stats(const float* __restrict__ A, int lda, int koff,
                                                  const float* __restrict__ W,
                                                  float* __restrict__ P,
                                                  float* __restrict__ stats,
                                                  int K) {
    __shared__ float AsT[16][64];   // [k][row]
    __shared__ float Ws [16][64];   // [k][col]
    __shared__ float red[16][64];

    const int tid = threadIdx.x;
    const int tx = tid & 15;
    const int ty = tid >> 4;
    const int row0 = blockIdx.y * 64;
    const int col0 = blockIdx.x * 64;

    const int ar = tid >> 2;          // 0..63  (A row within tile)
    const int ac = (tid & 3) << 2;    // 0,4,8,12 (A k within tile)
    const int wr = tid >> 4;          // 0..15  (W k within tile)
    const int wc = (tid & 15) << 2;   // 0..60  (W col within tile)

    float acc[4][4] = {};

    for (int k0 = 0; k0 < K; k0 += 16) {
        float4 av = *(const float4*)(A + (size_t)(row0 + ar) * lda + (koff + k0 + ac));
        float4 wv = *(const float4*)(W + (size_t)(k0 + wr) * 256 + (col0 + wc));
        AsT[ac + 0][ar] = av.x;
        AsT[ac + 1][ar] = av.y;
        AsT[ac + 2][ar] = av.z;
        AsT[ac + 3][ar] = av.w;
        *(float4*)&Ws[wr][wc] = wv;
        __syncthreads();
#pragma unroll
        for (int kk = 0; kk < 16; ++kk) {
            float4 a4 = *(const float4*)&AsT[kk][ty * 4];
            float4 w4 = *(const float4*)&Ws[kk][tx * 4];
            acc[0][0] += a4.x * w4.x; acc[0][1] += a4.x * w4.y; acc[0][2] += a4.x * w4.z; acc[0][3] += a4.x * w4.w;
            acc[1][0] += a4.y * w4.x; acc[1][1] += a4.y * w4.y; acc[1][2] += a4.y * w4.z; acc[1][3] += a4.y * w4.w;
            acc[2][0] += a4.z * w4.x; acc[2][1] += a4.z * w4.y; acc[2][2] += a4.z * w4.z; acc[2][3] += a4.z * w4.w;
            acc[3][0] += a4.w * w4.x; acc[3][1] += a4.w * w4.y; acc[3][2] += a4.w * w4.z; acc[3][3] += a4.w * w4.w;
        }
        __syncthreads();
    }

    // write P tile
#pragma unroll
    for (int i = 0; i < 4; ++i) {
        float4 o = make_float4(acc[i][0], acc[i][1], acc[i][2], acc[i][3]);
        *(float4*)(P + (size_t)(row0 + ty * 4 + i) * 256 + col0 + tx * 4) = o;
    }

    // fused column stats: per-thread partials over its 4 rows
    float cs[4], cq[4];
#pragma unroll
    for (int j = 0; j < 4; ++j) {
        cs[j] = acc[0][j] + acc[1][j] + acc[2][j] + acc[3][j];
        cq[j] = acc[0][j] * acc[0][j] + acc[1][j] * acc[1][j] +
                acc[2][j] * acc[2][j] + acc[3][j] * acc[3][j];
    }
#pragma unroll
    for (int j = 0; j < 4; ++j) red[ty][tx * 4 + j] = cs[j];
    __syncthreads();
    if (tid < 64) {
        float s = 0.f;
#pragma unroll
        for (int t = 0; t < 16; ++t) s += red[t][tid];
        atomicAdd(&stats[col0 + tid], s);
    }
    __syncthreads();
#pragma unroll
    for (int j = 0; j < 4; ++j) red[ty][tx * 4 + j] = cq[j];
    __syncthreads();
    if (tid < 64) {
        float s = 0.f;
#pragma unroll
        for (int t = 0; t < 16; ++t) s += red[t][tid];
        atomicAdd(&stats[256 + col0 + tid], s);
    }
}

// ---------------- BN + GLU (+ optional residual) ----------------
// Reads P (B x 256), writes H (B x 128): H = n[:, :128] * sigmoid(n[:, 128:]) [ (+res)*sqrt(1/2) ]
template <bool RES>
__global__ __launch_bounds__(256) void norm_glu(const float* __restrict__ P,
                                                const float* __restrict__ stats,
                                                const float* __restrict__ g,
                                                const float* __restrict__ b,
                                                const float* __restrict__ res,
                                                float* __restrict__ H) {
    const int idx = blockIdx.x * 256 + threadIdx.x;  // 0 .. B*128
    const int row = idx >> 7, c = idx & 127;

    float mean_a = stats[c] * INV_B;
    float var_a  = stats[256 + c] * INV_B - mean_a * mean_a;
    float sa = g[c] * rsqrtf(var_a + BN_EPS);
    float ba = b[c] - mean_a * sa;

    const int cg = c + 128;
    float mean_g = stats[cg] * INV_B;
    float var_g  = stats[256 + cg] * INV_B - mean_g * mean_g;
    float sg = g[cg] * rsqrtf(var_g + BN_EPS);
    float bg = b[cg] - mean_g * sg;

    const size_t pbase = (size_t)row * 256;
    float na = P[pbase + c] * sa + ba;
    float ng = P[pbase + cg] * sg + bg;
    float v = na * (1.0f / (1.0f + __expf(-ng)));
    if (RES) v = (v + res[idx]) * SQRT_HALF;
    H[idx] = v;
}

// ---------------- coef BN -> softmax -> mask/compl/entropy ----------------
// One block per row (256 threads = 256 features).
__global__ __launch_bounds__(256) void coef_mask(const float* __restrict__ Pc,
                                                 const float* __restrict__ stats,
                                                 const float* __restrict__ gc,
                                                 const float* __restrict__ bc,
                                                 const float* __restrict__ x_bn,
                                                 float* __restrict__ cmpl,
                                                 float* __restrict__ masked,
                                                 float* __restrict__ ent) {
    const int row = blockIdx.x;
    const int t = threadIdx.x;
    const int wid = t >> 6, lane = t & 63;
    __shared__ float rmax[4], rsum[4], rent[4];

    float mean = stats[t] * INV_B;
    float var  = stats[256 + t] * INV_B - mean * mean;
    float sc   = gc[t] * rsqrtf(var + BN_EPS);
    float sh   = bc[t] - mean * sc;

    const size_t idx = (size_t)row * 256 + t;
    float n  = Pc[idx] * sc + sh;
    float cl = cmpl[idx];
    float l  = n * cl;

    float wm = waveMax(l);
    if (lane == 0) rmax[wid] = wm;
    __syncthreads();
    float mx = fmaxf(fmaxf(rmax[0], rmax[1]), fmaxf(rmax[2], rmax[3]));

    float e = __expf(l - mx);
    float sw = waveSum(e);
    if (lane == 0) rsum[wid] = sw;
    __syncthreads();
    float denom = rsum[0] + rsum[1] + rsum[2] + rsum[3];
    float m = e / denom;

    float et = -m * __logf(m + SM_EPS);
    float se = waveSum(et);
    if (lane == 0) rent[wid] = se;
    __syncthreads();
    if (t == 0) {
        // accumulate mean over rows, already divided by (S-1)=5
        atomicAdd(ent, (rent[0] + rent[1] + rent[2] + rent[3]) * (INV_B * 0.2f));
    }

    cmpl[idx]   = cl * (1.5f - m);
    masked[idx] = m * x_bn[idx];
}

__global__ void write_ent(const float* __restrict__ ent, float* __restrict__ dst) {
    dst[0] = ent[0];
}

// ---------------- host orchestration ----------------
extern "C" void kernel_launch(void* const* d_in, const int* in_sizes, int n_in,
                              void* d_out, int out_size, void* d_ws, size_t ws_size,
                              hipStream_t stream) {
    const float* x     = (const float*)d_in[0];
    const float* enc_g = (const float*)d_in[1];
    const float* enc_b = (const float*)d_in[2];
    const float* W1 = (const float*)d_in[3];
    const float* g1 = (const float*)d_in[4];
    const float* b1 = (const float*)d_in[5];
    const float* W2 = (const float*)d_in[6];
    const float* g2 = (const float*)d_in[7];
    const float* b2 = (const float*)d_in[8];
    const float* W3 = (const float*)d_in[9];
    const float* g3 = (const float*)d_in[10];
    const float* b3 = (const float*)d_in[11];
    const float* W4 = (const float*)d_in[12];
    const float* g4 = (const float*)d_in[13];
    const float* b4 = (const float*)d_in[14];
    const float* Wc = (const float*)d_in[15];
    const float* gc = (const float*)d_in[16];
    const float* bc = (const float*)d_in[17];
    float* out = (float*)d_out;

    // workspace layout (floats)
    float* ws = (float*)d_ws;
    const size_t NBF = (size_t)BSZ * FDIM;   // 8388608
    const size_t NBH = (size_t)BSZ * HDIM;   // 4194304
    float* x_bn   = ws;
    float* masked = x_bn + NBF;
    float* cmpl   = masked + NBF;
    float* P      = cmpl + NBF;
    float* hA     = P + NBF;
    float* hB     = hA + NBH;
    float* hC     = hB + NBH;
    float* stats  = hC + NBH;                // 26 slots * 512
    float* ent    = stats + 26 * 512;        // 1 float

    hipMemsetAsync(stats, 0, (26 * 512 + 1) * sizeof(float), stream);

    // encoder BN
    colstats<<<512, 256, 0, stream>>>(x, stats);
    norm_x<<<BSZ, 256, 0, stream>>>(x, stats, enc_g, enc_b, x_bn, cmpl, out);

    const dim3 ggrid(4, 512);        // (N/64, B/64)
    const int NGLU = (BSZ * HDIM) / 256;  // 16384

    for (int ni = 0; ni < 5; ++ni) {
        float* s1 = stats + (size_t)(1 + ni * 5 + 0) * 512;
        float* s2 = stats + (size_t)(1 + ni * 5 + 1) * 512;
        float* s3 = stats + (size_t)(1 + ni * 5 + 2) * 512;
        float* s4 = stats + (size_t)(1 + ni * 5 + 3) * 512;
        float* s5 = stats + (size_t)(1 + ni * 5 + 4) * 512;

        const float* in1 = (ni == 0) ? x_bn : masked;

        gemm_stats<<<ggrid, 256, 0, stream>>>(in1, 256, 0, W1, P, s1, 256);
        norm_glu<false><<<NGLU, 256, 0, stream>>>(P, s1, g1, b1, nullptr, hA);

        gemm_stats<<<ggrid, 256, 0, stream>>>(hA, 128, 0, W2, P, s2, 128);
        norm_glu<true><<<NGLU, 256, 0, stream>>>(P, s2, g2, b2, hA, hB);

        gemm_stats<<<ggrid, 256, 0, stream>>>(hB, 128, 0, W3 + (size_t)ni * HDIM * 256, P, s3, 128);
        norm_glu<true><<<NGLU, 256, 0, stream>>>(P, s3, g3 + ni * 256, b3 + ni * 256, hB, hC);

        gemm_stats<<<ggrid, 256, 0, stream>>>(hC, 128, 0, W4 + (size_t)ni * HDIM * 256, P, s4, 128);
        norm_glu<true><<<NGLU, 256, 0, stream>>>(P, s4, g4 + ni * 256, b4 + ni * 256, hC, hA);

        // fc = h4[:, 64:128]  -> coef GEMM (K=64), no GLU
        gemm_stats<<<ggrid, 256, 0, stream>>>(hA, 128, 64, Wc + (size_t)ni * OUTD * 256, P, s5, 64);
        coef_mask<<<BSZ, 256, 0, stream>>>(P, s5, gc + ni * 256, bc + ni * 256,
                                           x_bn, cmpl, masked, ent);
    }

    write_ent<<<1, 1, 0, stream>>>(ent, out + (size_t)BSZ * OUTD);
}

// Round 2
// 1758.797 us; speedup vs baseline: 2.0373x; 2.0373x over previous
//
#include <hip/hip_runtime.h>
#include <math.h>

// Problem constants
#define BSZ   32768
#define FDIM  256
#define HDIM  128
#define OUTD  64
#define SQRT_HALF 0.70710678118654752f
#define BN_EPS 1e-5f
#define SM_EPS 1e-5f
#define INV_B (1.0f / 32768.0f)

// ---------------- wave reduce helpers (butterfly: every lane gets result) ----------------
__device__ inline float waveMaxAll(float v) {
#pragma unroll
    for (int m = 32; m > 0; m >>= 1) v = fmaxf(v, __shfl_xor(v, m, 64));
    return v;
}
__device__ inline float waveSumAll(float v) {
#pragma unroll
    for (int m = 32; m > 0; m >>= 1) v += __shfl_xor(v, m, 64);
    return v;
}

// ---------------- column stats for x (B x 256) ----------------
__global__ __launch_bounds__(256) void colstats(const float* __restrict__ X,
                                                float* __restrict__ stats) {
    const int c = threadIdx.x;
    float s = 0.f, q = 0.f;
    for (int r = blockIdx.x; r < BSZ; r += gridDim.x) {
        float v = X[(size_t)r * FDIM + c];
        s += v; q += v * v;
    }
    atomicAdd(&stats[c], s);
    atomicAdd(&stats[FDIM + c], q);
}

// ---------------- normalize x, write out=5*relu(x_bn[:, :64]), init compl ----------------
__global__ __launch_bounds__(256) void norm_x(const float* __restrict__ x,
                                              const float* __restrict__ stats,
                                              const float* __restrict__ g,
                                              const float* __restrict__ b,
                                              float* __restrict__ x_bn,
                                              float* __restrict__ cmpl,
                                              float* __restrict__ out) {
    const int idx = blockIdx.x * 256 + threadIdx.x;   // 0 .. B*256
    const int row = idx >> 8, c = idx & 255;
    float mean = stats[c] * INV_B;
    float var  = stats[FDIM + c] * INV_B - mean * mean;
    float sc   = g[c] * rsqrtf(var + BN_EPS);
    float sh   = b[c] - mean * sc;
    float n = x[idx] * sc + sh;
    x_bn[idx] = n;
    cmpl[idx] = 1.0f;
    if (c < OUTD) out[(size_t)row * OUTD + c] = 5.0f * fmaxf(n, 0.0f);
}

// ---------------- tiled fp32 GEMM with fused column stats ----------------
// C(B x 256) = A(B x K) @ W(K x 256); also accumulates per-column sum/sumsq into stats[512].
// A accessed as A[row*lda + koff + k].
__global__ __launch_bounds__(256) void gemm_stats(const float* __restrict__ A, int lda, int koff,
                                                  const float* __restrict__ W,
                                                  float* __restrict__ P,
                                                  float* __restrict__ stats,
                                                  int K) {
    __shared__ float AsT[16][64];   // [k][row]
    __shared__ float Ws [16][64];   // [k][col]
    __shared__ float red[16][64];

    const int tid = threadIdx.x;
    const int tx = tid & 15;
    const int ty = tid >> 4;
    const int row0 = blockIdx.y * 64;
    const int col0 = blockIdx.x * 64;

    const int ar = tid >> 2;          // 0..63  (A row within tile)
    const int ac = (tid & 3) << 2;    // 0,4,8,12 (A k within tile)
    const int wr = tid >> 4;          // 0..15  (W k within tile)
    const int wc = (tid & 15) << 2;   // 0..60  (W col within tile)

    float acc[4][4] = {};

    for (int k0 = 0; k0 < K; k0 += 16) {
        float4 av = *(const float4*)(A + (size_t)(row0 + ar) * lda + (koff + k0 + ac));
        float4 wv = *(const float4*)(W + (size_t)(k0 + wr) * 256 + (col0 + wc));
        AsT[ac + 0][ar] = av.x;
        AsT[ac + 1][ar] = av.y;
        AsT[ac + 2][ar] = av.z;
        AsT[ac + 3][ar] = av.w;
        *(float4*)&Ws[wr][wc] = wv;
        __syncthreads();
#pragma unroll
        for (int kk = 0; kk < 16; ++kk) {
            float4 a4 = *(const float4*)&AsT[kk][ty * 4];
            float4 w4 = *(const float4*)&Ws[kk][tx * 4];
            acc[0][0] += a4.x * w4.x; acc[0][1] += a4.x * w4.y; acc[0][2] += a4.x * w4.z; acc[0][3] += a4.x * w4.w;
            acc[1][0] += a4.y * w4.x; acc[1][1] += a4.y * w4.y; acc[1][2] += a4.y * w4.z; acc[1][3] += a4.y * w4.w;
            acc[2][0] += a4.z * w4.x; acc[2][1] += a4.z * w4.y; acc[2][2] += a4.z * w4.z; acc[2][3] += a4.z * w4.w;
            acc[3][0] += a4.w * w4.x; acc[3][1] += a4.w * w4.y; acc[3][2] += a4.w * w4.z; acc[3][3] += a4.w * w4.w;
        }
        __syncthreads();
    }

    // write P tile
#pragma unroll
    for (int i = 0; i < 4; ++i) {
        float4 o = make_float4(acc[i][0], acc[i][1], acc[i][2], acc[i][3]);
        *(float4*)(P + (size_t)(row0 + ty * 4 + i) * 256 + col0 + tx * 4) = o;
    }

    // fused column stats: per-thread partials over its 4 rows
    float cs[4], cq[4];
#pragma unroll
    for (int j = 0; j < 4; ++j) {
        cs[j] = acc[0][j] + acc[1][j] + acc[2][j] + acc[3][j];
        cq[j] = acc[0][j] * acc[0][j] + acc[1][j] * acc[1][j] +
                acc[2][j] * acc[2][j] + acc[3][j] * acc[3][j];
    }
#pragma unroll
    for (int j = 0; j < 4; ++j) red[ty][tx * 4 + j] = cs[j];
    __syncthreads();
    if (tid < 64) {
        float s = 0.f;
#pragma unroll
        for (int t = 0; t < 16; ++t) s += red[t][tid];
        atomicAdd(&stats[col0 + tid], s);
    }
    __syncthreads();
#pragma unroll
    for (int j = 0; j < 4; ++j) red[ty][tx * 4 + j] = cq[j];
    __syncthreads();
    if (tid < 64) {
        float s = 0.f;
#pragma unroll
        for (int t = 0; t < 16; ++t) s += red[t][tid];
        atomicAdd(&stats[256 + col0 + tid], s);
    }
}

// ---------------- BN + GLU (+ optional residual) ----------------
template <bool RES>
__global__ __launch_bounds__(256) void norm_glu(const float* __restrict__ P,
                                                const float* __restrict__ stats,
                                                const float* __restrict__ g,
                                                const float* __restrict__ b,
                                                const float* __restrict__ res,
                                                float* __restrict__ H) {
    const int idx = blockIdx.x * 256 + threadIdx.x;  // 0 .. B*128
    const int row = idx >> 7, c = idx & 127;

    float mean_a = stats[c] * INV_B;
    float var_a  = stats[256 + c] * INV_B - mean_a * mean_a;
    float sa = g[c] * rsqrtf(var_a + BN_EPS);
    float ba = b[c] - mean_a * sa;

    const int cg = c + 128;
    float mean_g = stats[cg] * INV_B;
    float var_g  = stats[256 + cg] * INV_B - mean_g * mean_g;
    float sg = g[cg] * rsqrtf(var_g + BN_EPS);
    float bg = b[cg] - mean_g * sg;

    const size_t pbase = (size_t)row * 256;
    float na = P[pbase + c] * sa + ba;
    float ng = P[pbase + cg] * sg + bg;
    float v = na * (1.0f / (1.0f + __expf(-ng)));
    if (RES) v = (v + res[idx]) * SQRT_HALF;
    H[idx] = v;
}

// ---------------- coef BN -> softmax -> mask/compl/entropy ----------------
// ONE WAVE PER ROW: 64 lanes x 4 features (float4). No barriers.
// Entropy atomics spread over 256 slots to avoid single-address serialization.
__global__ __launch_bounds__(256) void coef_mask(const float* __restrict__ Pc,
                                                 const float* __restrict__ stats,
                                                 const float* __restrict__ gc,
                                                 const float* __restrict__ bc,
                                                 const float* __restrict__ x_bn,
                                                 float* __restrict__ cmpl,
                                                 float* __restrict__ masked,
                                                 float* __restrict__ ent) {
    const int w    = threadIdx.x >> 6;       // wave 0..3
    const int lane = threadIdx.x & 63;
    const int row  = blockIdx.x * 4 + w;     // grid = B/4
    const int c    = lane << 2;              // feature base 0..252

    // per-feature BN affine (broadcast across rows; each lane computes its 4)
    float4 sv = *(const float4*)&stats[c];
    float4 qv = *(const float4*)&stats[256 + c];
    float4 gv = *(const float4*)&gc[c];
    float4 bv = *(const float4*)&bc[c];

    float mean, var;
    float scl[4], shf[4];
    mean = sv.x * INV_B; var = qv.x * INV_B - mean * mean;
    scl[0] = gv.x * rsqrtf(var + BN_EPS); shf[0] = bv.x - mean * scl[0];
    mean = sv.y * INV_B; var = qv.y * INV_B - mean * mean;
    scl[1] = gv.y * rsqrtf(var + BN_EPS); shf[1] = bv.y - mean * scl[1];
    mean = sv.z * INV_B; var = qv.z * INV_B - mean * mean;
    scl[2] = gv.z * rsqrtf(var + BN_EPS); shf[2] = bv.z - mean * scl[2];
    mean = sv.w * INV_B; var = qv.w * INV_B - mean * mean;
    scl[3] = gv.w * rsqrtf(var + BN_EPS); shf[3] = bv.w - mean * scl[3];

    const size_t idx = (size_t)row * 256 + c;
    float4 p  = *(const float4*)&Pc[idx];
    float4 cl = *(const float4*)&cmpl[idx];
    float4 xb = *(const float4*)&x_bn[idx];

    float l[4];
    l[0] = (p.x * scl[0] + shf[0]) * cl.x;
    l[1] = (p.y * scl[1] + shf[1]) * cl.y;
    l[2] = (p.z * scl[2] + shf[2]) * cl.z;
    l[3] = (p.w * scl[3] + shf[3]) * cl.w;

    float mx = fmaxf(fmaxf(l[0], l[1]), fmaxf(l[2], l[3]));
    mx = waveMaxAll(mx);

    float e[4];
    e[0] = __expf(l[0] - mx); e[1] = __expf(l[1] - mx);
    e[2] = __expf(l[2] - mx); e[3] = __expf(l[3] - mx);
    float s = e[0] + e[1] + e[2] + e[3];
    s = waveSumAll(s);
    float inv = 1.0f / s;

    float m[4];
    m[0] = e[0] * inv; m[1] = e[1] * inv; m[2] = e[2] * inv; m[3] = e[3] * inv;

    float et = -m[0] * __logf(m[0] + SM_EPS) - m[1] * __logf(m[1] + SM_EPS)
             - m[2] * __logf(m[2] + SM_EPS) - m[3] * __logf(m[3] + SM_EPS);
    et = waveSumAll(et);
    if (lane == 0) atomicAdd(&ent[row & 255], et * (INV_B * 0.2f));

    float4 co, mo;
    co.x = cl.x * (1.5f - m[0]); co.y = cl.y * (1.5f - m[1]);
    co.z = cl.z * (1.5f - m[2]); co.w = cl.w * (1.5f - m[3]);
    mo.x = m[0] * xb.x; mo.y = m[1] * xb.y; mo.z = m[2] * xb.z; mo.w = m[3] * xb.w;
    *(float4*)&cmpl[idx]   = co;
    *(float4*)&masked[idx] = mo;
}

__global__ __launch_bounds__(64) void write_ent(const float* __restrict__ ent,
                                                float* __restrict__ dst) {
    const int lane = threadIdx.x;
    float v = ent[lane] + ent[lane + 64] + ent[lane + 128] + ent[lane + 192];
    v = waveSumAll(v);
    if (lane == 0) dst[0] = v;
}

// ---------------- host orchestration ----------------
extern "C" void kernel_launch(void* const* d_in, const int* in_sizes, int n_in,
                              void* d_out, int out_size, void* d_ws, size_t ws_size,
                              hipStream_t stream) {
    const float* x     = (const float*)d_in[0];
    const float* enc_g = (const float*)d_in[1];
    const float* enc_b = (const float*)d_in[2];
    const float* W1 = (const float*)d_in[3];
    const float* g1 = (const float*)d_in[4];
    const float* b1 = (const float*)d_in[5];
    const float* W2 = (const float*)d_in[6];
    const float* g2 = (const float*)d_in[7];
    const float* b2 = (const float*)d_in[8];
    const float* W3 = (const float*)d_in[9];
    const float* g3 = (const float*)d_in[10];
    const float* b3 = (const float*)d_in[11];
    const float* W4 = (const float*)d_in[12];
    const float* g4 = (const float*)d_in[13];
    const float* b4 = (const float*)d_in[14];
    const float* Wc = (const float*)d_in[15];
    const float* gc = (const float*)d_in[16];
    const float* bc = (const float*)d_in[17];
    float* out = (float*)d_out;

    // workspace layout (floats)
    float* ws = (float*)d_ws;
    const size_t NBF = (size_t)BSZ * FDIM;   // 8388608
    const size_t NBH = (size_t)BSZ * HDIM;   // 4194304
    float* x_bn   = ws;
    float* masked = x_bn + NBF;
    float* cmpl   = masked + NBF;
    float* P      = cmpl + NBF;
    float* hA     = P + NBF;
    float* hB     = hA + NBH;
    float* hC     = hB + NBH;
    float* stats  = hC + NBH;                // 26 slots * 512
    float* ent    = stats + 26 * 512;        // 256 floats

    hipMemsetAsync(stats, 0, (26 * 512 + 256) * sizeof(float), stream);

    // encoder BN
    colstats<<<512, 256, 0, stream>>>(x, stats);
    norm_x<<<BSZ, 256, 0, stream>>>(x, stats, enc_g, enc_b, x_bn, cmpl, out);

    const dim3 ggrid(4, 512);        // (N/64, B/64)
    const int NGLU = (BSZ * HDIM) / 256;  // 16384

    for (int ni = 0; ni < 5; ++ni) {
        float* s1 = stats + (size_t)(1 + ni * 5 + 0) * 512;
        float* s2 = stats + (size_t)(1 + ni * 5 + 1) * 512;
        float* s3 = stats + (size_t)(1 + ni * 5 + 2) * 512;
        float* s4 = stats + (size_t)(1 + ni * 5 + 3) * 512;
        float* s5 = stats + (size_t)(1 + ni * 5 + 4) * 512;

        const float* in1 = (ni == 0) ? x_bn : masked;

        gemm_stats<<<ggrid, 256, 0, stream>>>(in1, 256, 0, W1, P, s1, 256);
        norm_glu<false><<<NGLU, 256, 0, stream>>>(P, s1, g1, b1, nullptr, hA);

        gemm_stats<<<ggrid, 256, 0, stream>>>(hA, 128, 0, W2, P, s2, 128);
        norm_glu<true><<<NGLU, 256, 0, stream>>>(P, s2, g2, b2, hA, hB);

        gemm_stats<<<ggrid, 256, 0, stream>>>(hB, 128, 0, W3 + (size_t)ni * HDIM * 256, P, s3, 128);
        norm_glu<true><<<NGLU, 256, 0, stream>>>(P, s3, g3 + ni * 256, b3 + ni * 256, hB, hC);

        gemm_stats<<<ggrid, 256, 0, stream>>>(hC, 128, 0, W4 + (size_t)ni * HDIM * 256, P, s4, 128);
        norm_glu<true><<<NGLU, 256, 0, stream>>>(P, s4, g4 + ni * 256, b4 + ni * 256, hC, hA);

        // fc = h4[:, 64:128]  -> coef GEMM (K=64), no GLU
        gemm_stats<<<ggrid, 256, 0, stream>>>(hA, 128, 64, Wc + (size_t)ni * OUTD * 256, P, s5, 64);
        coef_mask<<<BSZ / 4, 256, 0, stream>>>(P, s5, gc + ni * 256, bc + ni * 256,
                                               x_bn, cmpl, masked, ent);
    }

    write_ent<<<1, 64, 0, stream>>>(ent, out + (size_t)BSZ * OUTD);
}

// Round 3
// 1037.292 us; speedup vs baseline: 3.4544x; 1.6956x over previous
//
#include <hip/hip_runtime.h>
#include <math.h>

#define BSZ   32768
#define FDIM  256
#define HDIM  128
#define OUTD  64
#define SQRT_HALF 0.70710678118654752f
#define BN_EPS 1e-5f
#define SM_EPS 1e-5f
#define INV_B (1.0f / 32768.0f)

typedef __attribute__((ext_vector_type(8))) short bf16x8;
typedef __attribute__((ext_vector_type(4))) float f32x4;

__device__ __forceinline__ float b2f(unsigned short u) {
    return __uint_as_float(((unsigned int)u) << 16);
}
__device__ __forceinline__ unsigned short f2b(float f) {
    unsigned int u = __float_as_uint(f);
    u += 0x7fff + ((u >> 16) & 1);   // RNE
    return (unsigned short)(u >> 16);
}

// async global->LDS, 16B per lane; LDS dest = base + lane*16 (wave-uniform base)
__device__ __forceinline__ void async16(const void* g, void* l) {
    __builtin_amdgcn_global_load_lds(
        (const __attribute__((address_space(1))) void*)(uintptr_t)g,
        (__attribute__((address_space(3))) void*)(unsigned int)(uintptr_t)l,
        16, 0, 0);
}

__device__ inline float waveMaxAll(float v) {
#pragma unroll
    for (int m = 32; m > 0; m >>= 1) v = fmaxf(v, __shfl_xor(v, m, 64));
    return v;
}
__device__ inline float waveSumAll(float v) {
#pragma unroll
    for (int m = 32; m > 0; m >>= 1) v += __shfl_xor(v, m, 64);
    return v;
}

// ---------------- weight prep: fp32 (K x 256) -> bf16 transposed (256 x K) ----------------
__global__ __launch_bounds__(256) void prep_w(
    const float* __restrict__ W1, const float* __restrict__ W2,
    const float* __restrict__ W3, const float* __restrict__ W4,
    const float* __restrict__ Wc,
    unsigned short* __restrict__ W1t, unsigned short* __restrict__ W2t,
    unsigned short* __restrict__ W3t, unsigned short* __restrict__ W4t,
    unsigned short* __restrict__ Wct)
{
    const int m = blockIdx.x, kz = blockIdx.y, n = threadIdx.x;
    const float* src; unsigned short* dst; int K;
    if (m == 0)      { src = W1;                        dst = W1t;               K = 256; }
    else if (m == 1) { src = W2;                        dst = W2t;               K = 128; }
    else if (m < 7)  { int i = m - 2;  src = W3 + (size_t)i * 128 * 256; dst = W3t + (size_t)i * 32768; K = 128; }
    else if (m < 12) { int i = m - 7;  src = W4 + (size_t)i * 128 * 256; dst = W4t + (size_t)i * 32768; K = 128; }
    else             { int i = m - 12; src = Wc + (size_t)i * 64 * 256;  dst = Wct + (size_t)i * 16384; K = 64; }
    const int k0 = kz * 32;
    if (k0 >= K) return;
    for (int k = k0; k < k0 + 32; ++k)
        dst[(size_t)n * K + k] = f2b(src[(size_t)k * 256 + n]);
}

// ---------------- column stats for x (B x 256) ----------------
__global__ __launch_bounds__(256) void colstats(const float* __restrict__ X,
                                                float* __restrict__ stats) {
    const int c = threadIdx.x;
    float s = 0.f, q = 0.f;
    for (int r = blockIdx.x; r < BSZ; r += gridDim.x) {
        float v = X[(size_t)r * FDIM + c];
        s += v; q += v * v;
    }
    atomicAdd(&stats[c], s);
    atomicAdd(&stats[FDIM + c], q);
}

// ---------------- normalize x -> xb(bf16), out = 5*relu(x_bn[:, :64]), init compl ----------------
__global__ __launch_bounds__(256) void norm_x(const float* __restrict__ x,
                                              const float* __restrict__ stats,
                                              const float* __restrict__ g,
                                              const float* __restrict__ b,
                                              unsigned short* __restrict__ xb,
                                              float* __restrict__ cmpl,
                                              float* __restrict__ out) {
    const int idx = blockIdx.x * 256 + threadIdx.x;
    const int row = idx >> 8, c = idx & 255;
    float mean = stats[c] * INV_B;
    float var  = stats[FDIM + c] * INV_B - mean * mean;
    float sc   = g[c] * rsqrtf(var + BN_EPS);
    float sh   = b[c] - mean * sc;
    float n = x[idx] * sc + sh;
    xb[idx] = f2b(n);
    cmpl[idx] = 1.0f;
    if (c < OUTD) out[(size_t)row * OUTD + c] = 5.0f * fmaxf(n, 0.0f);
}

// ---------------- bf16 MFMA GEMM with fused column stats ----------------
// P(B x 256 bf16) = A(B x K bf16, rows lda, col offset koff) @ Wt^T
// Wt is pre-transposed: Wt[n][k], n in [0,256), k in [0,K)
__global__ __launch_bounds__(256) void gemm_bf16(
    const unsigned short* __restrict__ A, int lda, int koff,
    const unsigned short* __restrict__ Wt, int K,
    unsigned short* __restrict__ P,
    float* __restrict__ stats)
{
    __shared__ short As[128 * 32];   // [row][k] 8 KiB
    __shared__ short Bs[128 * 32];   // [n][k]   8 KiB
    __shared__ float redS[2][128];
    __shared__ float redQ[2][128];

    const int tid  = threadIdx.x;
    const int wave = tid >> 6;
    const int lane = tid & 63;
    const int waveM = wave >> 1, waveN = wave & 1;
    const int row0 = blockIdx.y * 128;
    const int col0 = blockIdx.x * 128;

    const int sr = lane >> 2;        // row within 16-row staging group
    const int sc = (lane & 3) * 8;   // k offset of this lane's 16B chunk

    f32x4 acc[4][4];
#pragma unroll
    for (int i = 0; i < 4; ++i)
#pragma unroll
        for (int j = 0; j < 4; ++j)
            acc[i][j] = (f32x4){0.f, 0.f, 0.f, 0.f};

    const int fm = lane & 15;          // frag m/n index
    const int fq = (lane >> 4) * 8;    // frag k base

    for (int k0 = 0; k0 < K; k0 += 32) {
#pragma unroll
        for (int t = 0; t < 2; ++t) {
            const int rr = (wave * 2 + t) * 16 + sr;
            async16(A  + (size_t)(row0 + rr) * lda + koff + k0 + sc,
                    (void*)(As + (wave * 2 + t) * 512 + lane * 8));
            async16(Wt + (size_t)(col0 + rr) * K + k0 + sc,
                    (void*)(Bs + (wave * 2 + t) * 512 + lane * 8));
        }
        __syncthreads();

        bf16x8 af[4], bfr[4];
#pragma unroll
        for (int i = 0; i < 4; ++i)
            af[i] = *(const bf16x8*)(As + (waveM * 64 + i * 16 + fm) * 32 + fq);
#pragma unroll
        for (int j = 0; j < 4; ++j)
            bfr[j] = *(const bf16x8*)(Bs + (waveN * 64 + j * 16 + fm) * 32 + fq);
#pragma unroll
        for (int i = 0; i < 4; ++i)
#pragma unroll
            for (int j = 0; j < 4; ++j)
                acc[i][j] = __builtin_amdgcn_mfma_f32_16x16x32_bf16(af[i], bfr[j], acc[i][j], 0, 0, 0);
        __syncthreads();
    }

    // ---- write P tile (bf16) ----  C/D layout: col = lane&15, row = quad*4 + reg
    const int orow = row0 + waveM * 64 + (lane >> 4) * 4;
    const int ocol = col0 + waveN * 64 + fm;
#pragma unroll
    for (int i = 0; i < 4; ++i)
#pragma unroll
        for (int j = 0; j < 4; ++j)
#pragma unroll
            for (int r = 0; r < 4; ++r)
                P[(size_t)(orow + i * 16 + r) * 256 + (ocol + j * 16)] = f2b(acc[i][j][r]);

    // ---- fused column stats ----
#pragma unroll
    for (int j = 0; j < 4; ++j) {
        float s = 0.f, q = 0.f;
#pragma unroll
        for (int i = 0; i < 4; ++i)
#pragma unroll
            for (int r = 0; r < 4; ++r) {
                float v = acc[i][j][r];
                s += v; q += v * v;
            }
        s += __shfl_xor(s, 16, 64); s += __shfl_xor(s, 32, 64);
        q += __shfl_xor(q, 16, 64); q += __shfl_xor(q, 32, 64);
        if (lane < 16) {
            redS[waveM][waveN * 64 + j * 16 + lane] = s;
            redQ[waveM][waveN * 64 + j * 16 + lane] = q;
        }
    }
    __syncthreads();
    if (tid < 128) {
        atomicAdd(&stats[col0 + tid], redS[0][tid] + redS[1][tid]);
    } else {
        const int t = tid - 128;
        atomicAdd(&stats[256 + col0 + t], redQ[0][t] + redQ[1][t]);
    }
}

// ---------------- BN + GLU (+ optional residual), all bf16 activations ----------------
template <bool RES>
__global__ __launch_bounds__(256) void norm_glu(const unsigned short* __restrict__ P,
                                                const float* __restrict__ stats,
                                                const float* __restrict__ g,
                                                const float* __restrict__ b,
                                                const unsigned short* __restrict__ res,
                                                unsigned short* __restrict__ H) {
    const int i4 = blockIdx.x * 256 + threadIdx.x;   // B*32 total
    const int row = i4 >> 5;
    const int c = (i4 & 31) << 2;

    float4 s_a = *(const float4*)&stats[c];
    float4 q_a = *(const float4*)&stats[256 + c];
    float4 g_a = *(const float4*)&g[c];
    float4 b_a = *(const float4*)&b[c];
    float4 s_g = *(const float4*)&stats[c + 128];
    float4 q_g = *(const float4*)&stats[256 + c + 128];
    float4 g_g = *(const float4*)&g[c + 128];
    float4 b_g = *(const float4*)&b[c + 128];

    ushort4 pa = *(const ushort4*)(P + (size_t)row * 256 + c);
    ushort4 pg = *(const ushort4*)(P + (size_t)row * 256 + c + 128);
    ushort4 rv = {0, 0, 0, 0};
    if (RES) rv = *(const ushort4*)(res + (size_t)row * 128 + c);

    const float* sa = (const float*)&s_a; const float* qa = (const float*)&q_a;
    const float* ga = (const float*)&g_a; const float* ba = (const float*)&b_a;
    const float* sg = (const float*)&s_g; const float* qg = (const float*)&q_g;
    const float* gg = (const float*)&g_g; const float* bg = (const float*)&b_g;
    const unsigned short* pav = (const unsigned short*)&pa;
    const unsigned short* pgv = (const unsigned short*)&pg;
    const unsigned short* rvv = (const unsigned short*)&rv;

    ushort4 outv;
    unsigned short* op = (unsigned short*)&outv;
#pragma unroll
    for (int e = 0; e < 4; ++e) {
        float ma = sa[e] * INV_B, va = qa[e] * INV_B - ma * ma;
        float scA = ga[e] * rsqrtf(va + BN_EPS), shA = ba[e] - ma * scA;
        float mg = sg[e] * INV_B, vg = qg[e] * INV_B - mg * mg;
        float scG = gg[e] * rsqrtf(vg + BN_EPS), shG = bg[e] - mg * scG;
        float na = b2f(pav[e]) * scA + shA;
        float ng = b2f(pgv[e]) * scG + shG;
        float v = na * (1.0f / (1.0f + __expf(-ng)));
        if (RES) v = (v + b2f(rvv[e])) * SQRT_HALF;
        op[e] = f2b(v);
    }
    *(ushort4*)(H + (size_t)row * 128 + c) = outv;
}

// ---------------- coef BN -> softmax -> mask/compl/entropy (one wave per row) ----------------
__global__ __launch_bounds__(256) void coef_mask(const unsigned short* __restrict__ Pc,
                                                 const float* __restrict__ stats,
                                                 const float* __restrict__ gc,
                                                 const float* __restrict__ bc,
                                                 const unsigned short* __restrict__ xb,
                                                 float* __restrict__ cmpl,
                                                 unsigned short* __restrict__ masked,
                                                 float* __restrict__ ent) {
    const int w    = threadIdx.x >> 6;
    const int lane = threadIdx.x & 63;
    const int row  = blockIdx.x * 4 + w;
    const int c    = lane << 2;

    float4 sv = *(const float4*)&stats[c];
    float4 qv = *(const float4*)&stats[256 + c];
    float4 gv = *(const float4*)&gc[c];
    float4 bv = *(const float4*)&bc[c];
    const float* svv = (const float*)&sv; const float* qvv = (const float*)&qv;
    const float* gvv = (const float*)&gv; const float* bvv = (const float*)&bv;

    float scl[4], shf[4];
#pragma unroll
    for (int e = 0; e < 4; ++e) {
        float mean = svv[e] * INV_B, var = qvv[e] * INV_B - mean * mean;
        scl[e] = gvv[e] * rsqrtf(var + BN_EPS);
        shf[e] = bvv[e] - mean * scl[e];
    }

    const size_t idx = (size_t)row * 256 + c;
    ushort4 pu = *(const ushort4*)(Pc + idx);
    float4 cl  = *(const float4*)&cmpl[idx];
    ushort4 xu = *(const ushort4*)(xb + idx);
    const unsigned short* puv = (const unsigned short*)&pu;
    const unsigned short* xuv = (const unsigned short*)&xu;
    const float* clv = (const float*)&cl;

    float l[4];
#pragma unroll
    for (int e = 0; e < 4; ++e) l[e] = (b2f(puv[e]) * scl[e] + shf[e]) * clv[e];

    float mx = waveMaxAll(fmaxf(fmaxf(l[0], l[1]), fmaxf(l[2], l[3])));
    float e0 = __expf(l[0] - mx), e1 = __expf(l[1] - mx),
          e2 = __expf(l[2] - mx), e3 = __expf(l[3] - mx);
    float inv = 1.0f / waveSumAll(e0 + e1 + e2 + e3);

    float m[4] = {e0 * inv, e1 * inv, e2 * inv, e3 * inv};

    float et = -m[0] * __logf(m[0] + SM_EPS) - m[1] * __logf(m[1] + SM_EPS)
             - m[2] * __logf(m[2] + SM_EPS) - m[3] * __logf(m[3] + SM_EPS);
    et = waveSumAll(et);
    if (lane == 0) atomicAdd(&ent[row & 255], et * (INV_B * 0.2f));

    float4 co;
    co.x = clv[0] * (1.5f - m[0]); co.y = clv[1] * (1.5f - m[1]);
    co.z = clv[2] * (1.5f - m[2]); co.w = clv[3] * (1.5f - m[3]);
    ushort4 mo;
    unsigned short* mop = (unsigned short*)&mo;
#pragma unroll
    for (int e = 0; e < 4; ++e) mop[e] = f2b(m[e] * b2f(xuv[e]));

    *(float4*)&cmpl[idx]   = co;
    *(ushort4*)&masked[idx] = mo;
}

__global__ __launch_bounds__(64) void write_ent(const float* __restrict__ ent,
                                                float* __restrict__ dst) {
    const int lane = threadIdx.x;
    float v = ent[lane] + ent[lane + 64] + ent[lane + 128] + ent[lane + 192];
    v = waveSumAll(v);
    if (lane == 0) dst[0] = v;
}

// ---------------- host orchestration ----------------
extern "C" void kernel_launch(void* const* d_in, const int* in_sizes, int n_in,
                              void* d_out, int out_size, void* d_ws, size_t ws_size,
                              hipStream_t stream) {
    const float* x     = (const float*)d_in[0];
    const float* enc_g = (const float*)d_in[1];
    const float* enc_b = (const float*)d_in[2];
    const float* W1 = (const float*)d_in[3];
    const float* g1 = (const float*)d_in[4];
    const float* b1 = (const float*)d_in[5];
    const float* W2 = (const float*)d_in[6];
    const float* g2 = (const float*)d_in[7];
    const float* b2 = (const float*)d_in[8];
    const float* W3 = (const float*)d_in[9];
    const float* g3 = (const float*)d_in[10];
    const float* b3 = (const float*)d_in[11];
    const float* W4 = (const float*)d_in[12];
    const float* g4 = (const float*)d_in[13];
    const float* b4 = (const float*)d_in[14];
    const float* Wc = (const float*)d_in[15];
    const float* gc = (const float*)d_in[16];
    const float* bc = (const float*)d_in[17];
    float* out = (float*)d_out;

    const size_t NBF = (size_t)BSZ * FDIM;   // 8388608
    const size_t NBH = (size_t)BSZ * HDIM;   // 4194304

    unsigned short* xb     = (unsigned short*)d_ws;
    unsigned short* masked = xb + NBF;
    unsigned short* Pb     = masked + NBF;
    unsigned short* hA     = Pb + NBF;
    unsigned short* hB     = hA + NBH;
    unsigned short* hC     = hB + NBH;
    unsigned short* W1t    = hC + NBH;            // 65536
    unsigned short* W2t    = W1t + 65536;         // 32768
    unsigned short* W3t    = W2t + 32768;         // 5*32768
    unsigned short* W4t    = W3t + 163840;        // 5*32768
    unsigned short* Wct    = W4t + 163840;        // 5*16384
    float* cmpl  = (float*)(Wct + 81920);
    float* stats = cmpl + NBF;                    // 26 slots * 512
    float* ent   = stats + 26 * 512;              // 256 floats

    hipMemsetAsync(stats, 0, (26 * 512 + 256) * sizeof(float), stream);

    prep_w<<<dim3(17, 8), 256, 0, stream>>>(W1, W2, W3, W4, Wc, W1t, W2t, W3t, W4t, Wct);
    colstats<<<512, 256, 0, stream>>>(x, stats);
    norm_x<<<BSZ, 256, 0, stream>>>(x, stats, enc_g, enc_b, xb, cmpl, out);

    const dim3 ggrid(2, 256);            // (N/128, B/128)
    const int NGLU = (BSZ * HDIM) / (256 * 4);   // 4096

    for (int ni = 0; ni < 5; ++ni) {
        float* s1 = stats + (size_t)(1 + ni * 5 + 0) * 512;
        float* s2 = stats + (size_t)(1 + ni * 5 + 1) * 512;
        float* s3 = stats + (size_t)(1 + ni * 5 + 2) * 512;
        float* s4 = stats + (size_t)(1 + ni * 5 + 3) * 512;
        float* s5 = stats + (size_t)(1 + ni * 5 + 4) * 512;

        const unsigned short* in1 = (ni == 0) ? xb : masked;

        gemm_bf16<<<ggrid, 256, 0, stream>>>(in1, 256, 0, W1t, 256, Pb, s1);
        norm_glu<false><<<NGLU, 256, 0, stream>>>(Pb, s1, g1, b1, nullptr, hA);

        gemm_bf16<<<ggrid, 256, 0, stream>>>(hA, 128, 0, W2t, 128, Pb, s2);
        norm_glu<true><<<NGLU, 256, 0, stream>>>(Pb, s2, g2, b2, hA, hB);

        gemm_bf16<<<ggrid, 256, 0, stream>>>(hB, 128, 0, W3t + (size_t)ni * 32768, 128, Pb, s3);
        norm_glu<true><<<NGLU, 256, 0, stream>>>(Pb, s3, g3 + ni * 256, b3 + ni * 256, hB, hC);

        gemm_bf16<<<ggrid, 256, 0, stream>>>(hC, 128, 0, W4t + (size_t)ni * 32768, 128, Pb, s4);
        norm_glu<true><<<NGLU, 256, 0, stream>>>(Pb, s4, g4 + ni * 256, b4 + ni * 256, hC, hA);

        gemm_bf16<<<ggrid, 256, 0, stream>>>(hA, 128, 64, Wct + (size_t)ni * 16384, 64, Pb, s5);
        coef_mask<<<BSZ / 4, 256, 0, stream>>>(Pb, s5, gc + ni * 256, bc + ni * 256,
                                               xb, cmpl, masked, ent);
    }

    write_ent<<<1, 64, 0, stream>>>(ent, out + (size_t)BSZ * OUTD);
}

// Round 4
// 830.116 us; speedup vs baseline: 4.3165x; 1.2496x over previous
//
#include <hip/hip_runtime.h>
#include <math.h>

#define BSZ   32768
#define FDIM  256
#define HDIM  128
#define OUTD  64
#define SQRT_HALF 0.70710678118654752f
#define BN_EPS 1e-5f
#define SM_EPS 1e-5f
#define INV_B (1.0f / 32768.0f)

typedef __attribute__((ext_vector_type(8))) short bf16x8;
typedef __attribute__((ext_vector_type(4))) float f32x4;

__device__ __forceinline__ float b2f(unsigned short u) {
    return __uint_as_float(((unsigned int)u) << 16);
}
__device__ __forceinline__ unsigned short f2b(float f) {
    unsigned int u = __float_as_uint(f);
    u += 0x7fff + ((u >> 16) & 1);   // RNE
    return (unsigned short)(u >> 16);
}

// async global->LDS, 16B per lane; LDS dest = base + lane*16 (wave-uniform base)
__device__ __forceinline__ void async16(const void* g, void* l) {
    __builtin_amdgcn_global_load_lds(
        (const __attribute__((address_space(1))) void*)(uintptr_t)g,
        (__attribute__((address_space(3))) void*)(unsigned int)(uintptr_t)l,
        16, 0, 0);
}

__device__ inline float waveMaxAll(float v) {
#pragma unroll
    for (int m = 32; m > 0; m >>= 1) v = fmaxf(v, __shfl_xor(v, m, 64));
    return v;
}
__device__ inline float waveSumAll(float v) {
#pragma unroll
    for (int m = 32; m > 0; m >>= 1) v += __shfl_xor(v, m, 64);
    return v;
}

// ---------------- weight prep: fp32 (K x 256) -> bf16 transposed (256 x K) ----------------
__global__ __launch_bounds__(256) void prep_w(
    const float* __restrict__ W1, const float* __restrict__ W2,
    const float* __restrict__ W3, const float* __restrict__ W4,
    const float* __restrict__ Wc,
    unsigned short* __restrict__ W1t, unsigned short* __restrict__ W2t,
    unsigned short* __restrict__ W3t, unsigned short* __restrict__ W4t,
    unsigned short* __restrict__ Wct)
{
    const int m = blockIdx.x, kz = blockIdx.y, n = threadIdx.x;
    const float* src; unsigned short* dst; int K;
    if (m == 0)      { src = W1;                        dst = W1t;               K = 256; }
    else if (m == 1) { src = W2;                        dst = W2t;               K = 128; }
    else if (m < 7)  { int i = m - 2;  src = W3 + (size_t)i * 128 * 256; dst = W3t + (size_t)i * 32768; K = 128; }
    else if (m < 12) { int i = m - 7;  src = W4 + (size_t)i * 128 * 256; dst = W4t + (size_t)i * 32768; K = 128; }
    else             { int i = m - 12; src = Wc + (size_t)i * 64 * 256;  dst = Wct + (size_t)i * 16384; K = 64; }
    const int k0 = kz * 32;
    if (k0 >= K) return;
    for (int k = k0; k < k0 + 32; ++k)
        dst[(size_t)n * K + k] = f2b(src[(size_t)k * 256 + n]);
}

// ---------------- column stats for x (B x 256) ----------------
__global__ __launch_bounds__(256) void colstats(const float* __restrict__ X,
                                                float* __restrict__ stats) {
    const int c = threadIdx.x;
    float s = 0.f, q = 0.f;
    for (int r = blockIdx.x; r < BSZ; r += gridDim.x) {
        float v = X[(size_t)r * FDIM + c];
        s += v; q += v * v;
    }
    atomicAdd(&stats[c], s);
    atomicAdd(&stats[FDIM + c], q);
}

// ---------------- normalize x -> xb(bf16), out = 5*relu(x_bn[:, :64]) ----------------
__global__ __launch_bounds__(256) void norm_x(const float* __restrict__ x,
                                              const float* __restrict__ stats,
                                              const float* __restrict__ g,
                                              const float* __restrict__ b,
                                              unsigned short* __restrict__ xb,
                                              float* __restrict__ out) {
    const int idx = blockIdx.x * 256 + threadIdx.x;
    const int row = idx >> 8, c = idx & 255;
    float mean = stats[c] * INV_B;
    float var  = stats[FDIM + c] * INV_B - mean * mean;
    float sc   = g[c] * rsqrtf(var + BN_EPS);
    float sh   = b[c] - mean * sc;
    float n = x[idx] * sc + sh;
    xb[idx] = f2b(n);
    if (c < OUTD) out[(size_t)row * OUTD + c] = 5.0f * fmaxf(n, 0.0f);
}

// ---------------- bf16 MFMA GEMM with fused column stats ----------------
__global__ __launch_bounds__(256) void gemm_bf16(
    const unsigned short* __restrict__ A, int lda, int koff,
    const unsigned short* __restrict__ Wt, int K,
    unsigned short* __restrict__ P,
    float* __restrict__ stats)
{
    __shared__ short As[128 * 32];   // [row][k] 8 KiB
    __shared__ short Bs[128 * 32];   // [n][k]   8 KiB
    __shared__ float redS[2][128];
    __shared__ float redQ[2][128];

    const int tid  = threadIdx.x;
    const int wave = tid >> 6;
    const int lane = tid & 63;
    const int waveM = wave >> 1, waveN = wave & 1;
    const int row0 = blockIdx.y * 128;
    const int col0 = blockIdx.x * 128;

    const int sr = lane >> 2;        // row within 16-row staging group
    const int sc = (lane & 3) * 8;   // k offset of this lane's 16B chunk

    f32x4 acc[4][4];
#pragma unroll
    for (int i = 0; i < 4; ++i)
#pragma unroll
        for (int j = 0; j < 4; ++j)
            acc[i][j] = (f32x4){0.f, 0.f, 0.f, 0.f};

    const int fm = lane & 15;          // frag m/n index
    const int fq = (lane >> 4) * 8;    // frag k base

    for (int k0 = 0; k0 < K; k0 += 32) {
#pragma unroll
        for (int t = 0; t < 2; ++t) {
            const int rr = (wave * 2 + t) * 16 + sr;
            async16(A  + (size_t)(row0 + rr) * lda + koff + k0 + sc,
                    (void*)(As + (wave * 2 + t) * 512 + lane * 8));
            async16(Wt + (size_t)(col0 + rr) * K + k0 + sc,
                    (void*)(Bs + (wave * 2 + t) * 512 + lane * 8));
        }
        __syncthreads();

        bf16x8 af[4], bfr[4];
#pragma unroll
        for (int i = 0; i < 4; ++i)
            af[i] = *(const bf16x8*)(As + (waveM * 64 + i * 16 + fm) * 32 + fq);
#pragma unroll
        for (int j = 0; j < 4; ++j)
            bfr[j] = *(const bf16x8*)(Bs + (waveN * 64 + j * 16 + fm) * 32 + fq);
#pragma unroll
        for (int i = 0; i < 4; ++i)
#pragma unroll
            for (int j = 0; j < 4; ++j)
                acc[i][j] = __builtin_amdgcn_mfma_f32_16x16x32_bf16(af[i], bfr[j], acc[i][j], 0, 0, 0);
        __syncthreads();
    }

    // ---- write P tile (bf16) ----  C/D layout: col = lane&15, row = quad*4 + reg
    const int orow = row0 + waveM * 64 + (lane >> 4) * 4;
    const int ocol = col0 + waveN * 64 + fm;
#pragma unroll
    for (int i = 0; i < 4; ++i)
#pragma unroll
        for (int j = 0; j < 4; ++j)
#pragma unroll
            for (int r = 0; r < 4; ++r)
                P[(size_t)(orow + i * 16 + r) * 256 + (ocol + j * 16)] = f2b(acc[i][j][r]);

    // ---- fused column stats ----
#pragma unroll
    for (int j = 0; j < 4; ++j) {
        float s = 0.f, q = 0.f;
#pragma unroll
        for (int i = 0; i < 4; ++i)
#pragma unroll
            for (int r = 0; r < 4; ++r) {
                float v = acc[i][j][r];
                s += v; q += v * v;
            }
        s += __shfl_xor(s, 16, 64); s += __shfl_xor(s, 32, 64);
        q += __shfl_xor(q, 16, 64); q += __shfl_xor(q, 32, 64);
        if (lane < 16) {
            redS[waveM][waveN * 64 + j * 16 + lane] = s;
            redQ[waveM][waveN * 64 + j * 16 + lane] = q;
        }
    }
    __syncthreads();
    if (tid < 128) {
        atomicAdd(&stats[col0 + tid], redS[0][tid] + redS[1][tid]);
    } else {
        const int t = tid - 128;
        atomicAdd(&stats[256 + col0 + t], redQ[0][t] + redQ[1][t]);
    }
}

// ---------------- BN + GLU (+ optional residual), all bf16 activations ----------------
template <bool RES>
__global__ __launch_bounds__(256) void norm_glu(const unsigned short* __restrict__ P,
                                                const float* __restrict__ stats,
                                                const float* __restrict__ g,
                                                const float* __restrict__ b,
                                                const unsigned short* __restrict__ res,
                                                unsigned short* __restrict__ H) {
    const int i4 = blockIdx.x * 256 + threadIdx.x;   // B*32 total
    const int row = i4 >> 5;
    const int c = (i4 & 31) << 2;

    float4 s_a = *(const float4*)&stats[c];
    float4 q_a = *(const float4*)&stats[256 + c];
    float4 g_a = *(const float4*)&g[c];
    float4 b_a = *(const float4*)&b[c];
    float4 s_g = *(const float4*)&stats[c + 128];
    float4 q_g = *(const float4*)&stats[256 + c + 128];
    float4 g_g = *(const float4*)&g[c + 128];
    float4 b_g = *(const float4*)&b[c + 128];

    ushort4 pa = *(const ushort4*)(P + (size_t)row * 256 + c);
    ushort4 pg = *(const ushort4*)(P + (size_t)row * 256 + c + 128);
    ushort4 rv = {0, 0, 0, 0};
    if (RES) rv = *(const ushort4*)(res + (size_t)row * 128 + c);

    const float* sa = (const float*)&s_a; const float* qa = (const float*)&q_a;
    const float* ga = (const float*)&g_a; const float* ba = (const float*)&b_a;
    const float* sg = (const float*)&s_g; const float* qg = (const float*)&q_g;
    const float* gg = (const float*)&g_g; const float* bg = (const float*)&b_g;
    const unsigned short* pav = (const unsigned short*)&pa;
    const unsigned short* pgv = (const unsigned short*)&pg;
    const unsigned short* rvv = (const unsigned short*)&rv;

    ushort4 outv;
    unsigned short* op = (unsigned short*)&outv;
#pragma unroll
    for (int e = 0; e < 4; ++e) {
        float ma = sa[e] * INV_B, va = qa[e] * INV_B - ma * ma;
        float scA = ga[e] * rsqrtf(va + BN_EPS), shA = ba[e] - ma * scA;
        float mg = sg[e] * INV_B, vg = qg[e] * INV_B - mg * mg;
        float scG = gg[e] * rsqrtf(vg + BN_EPS), shG = bg[e] - mg * scG;
        float na = b2f(pav[e]) * scA + shA;
        float ng = b2f(pgv[e]) * scG + shG;
        float v = na * (1.0f / (1.0f + __expf(-ng)));
        if (RES) v = (v + b2f(rvv[e])) * SQRT_HALF;
        op[e] = f2b(v);
    }
    *(ushort4*)(H + (size_t)row * 128 + c) = outv;
}

// ---------------- coef BN -> softmax -> mask/compl/entropy ----------------
// One wave per row; block-level entropy reduce -> 1 atomic/block into 128B-spread slots.
template <bool FIRST>
__global__ __launch_bounds__(256) void coef_mask(const unsigned short* __restrict__ Pc,
                                                 const float* __restrict__ stats,
                                                 const float* __restrict__ gc,
                                                 const float* __restrict__ bc,
                                                 const unsigned short* __restrict__ xb,
                                                 unsigned short* __restrict__ cmpl,
                                                 unsigned short* __restrict__ masked,
                                                 float* __restrict__ ent) {
    const int w    = threadIdx.x >> 6;
    const int lane = threadIdx.x & 63;
    const int row  = blockIdx.x * 4 + w;
    const int c    = lane << 2;
    __shared__ float went[4];

    float4 sv = *(const float4*)&stats[c];
    float4 qv = *(const float4*)&stats[256 + c];
    float4 gv = *(const float4*)&gc[c];
    float4 bv = *(const float4*)&bc[c];
    const float* svv = (const float*)&sv; const float* qvv = (const float*)&qv;
    const float* gvv = (const float*)&gv; const float* bvv = (const float*)&bv;

    float scl[4], shf[4];
#pragma unroll
    for (int e = 0; e < 4; ++e) {
        float mean = svv[e] * INV_B, var = qvv[e] * INV_B - mean * mean;
        scl[e] = gvv[e] * rsqrtf(var + BN_EPS);
        shf[e] = bvv[e] - mean * scl[e];
    }

    const size_t idx = (size_t)row * 256 + c;
    ushort4 pu = *(const ushort4*)(Pc + idx);
    ushort4 xu = *(const ushort4*)(xb + idx);
    const unsigned short* puv = (const unsigned short*)&pu;
    const unsigned short* xuv = (const unsigned short*)&xu;

    float cl[4] = {1.f, 1.f, 1.f, 1.f};
    if (!FIRST) {
        ushort4 cu = *(const ushort4*)(cmpl + idx);
        const unsigned short* cuv = (const unsigned short*)&cu;
#pragma unroll
        for (int e = 0; e < 4; ++e) cl[e] = b2f(cuv[e]);
    }

    float l[4];
#pragma unroll
    for (int e = 0; e < 4; ++e) l[e] = (b2f(puv[e]) * scl[e] + shf[e]) * cl[e];

    float mx = waveMaxAll(fmaxf(fmaxf(l[0], l[1]), fmaxf(l[2], l[3])));
    float e0 = __expf(l[0] - mx), e1 = __expf(l[1] - mx),
          e2 = __expf(l[2] - mx), e3 = __expf(l[3] - mx);
    float inv = 1.0f / waveSumAll(e0 + e1 + e2 + e3);

    float m[4] = {e0 * inv, e1 * inv, e2 * inv, e3 * inv};

    float et = -m[0] * __logf(m[0] + SM_EPS) - m[1] * __logf(m[1] + SM_EPS)
             - m[2] * __logf(m[2] + SM_EPS) - m[3] * __logf(m[3] + SM_EPS);
    et = waveSumAll(et);
    if (lane == 0) went[w] = et;
    __syncthreads();
    if (threadIdx.x == 0) {
        float v = went[0] + went[1] + went[2] + went[3];
        atomicAdd(&ent[(blockIdx.x & 255) << 5], v * (INV_B * 0.2f));
    }

    ushort4 co, mo;
    unsigned short* cop = (unsigned short*)&co;
    unsigned short* mop = (unsigned short*)&mo;
#pragma unroll
    for (int e = 0; e < 4; ++e) {
        cop[e] = f2b(cl[e] * (1.5f - m[e]));
        mop[e] = f2b(m[e] * b2f(xuv[e]));
    }
    *(ushort4*)&cmpl[idx]   = co;
    *(ushort4*)&masked[idx] = mo;
}

__global__ __launch_bounds__(64) void write_ent(const float* __restrict__ ent,
                                                float* __restrict__ dst) {
    const int lane = threadIdx.x;
    float v = 0.f;
#pragma unroll
    for (int i = 0; i < 4; ++i) v += ent[(lane + 64 * i) << 5];
    v = waveSumAll(v);
    if (lane == 0) dst[0] = v;
}

// ---------------- host orchestration ----------------
extern "C" void kernel_launch(void* const* d_in, const int* in_sizes, int n_in,
                              void* d_out, int out_size, void* d_ws, size_t ws_size,
                              hipStream_t stream) {
    const float* x     = (const float*)d_in[0];
    const float* enc_g = (const float*)d_in[1];
    const float* enc_b = (const float*)d_in[2];
    const float* W1 = (const float*)d_in[3];
    const float* g1 = (const float*)d_in[4];
    const float* b1 = (const float*)d_in[5];
    const float* W2 = (const float*)d_in[6];
    const float* g2 = (const float*)d_in[7];
    const float* b2 = (const float*)d_in[8];
    const float* W3 = (const float*)d_in[9];
    const float* g3 = (const float*)d_in[10];
    const float* b3 = (const float*)d_in[11];
    const float* W4 = (const float*)d_in[12];
    const float* g4 = (const float*)d_in[13];
    const float* b4 = (const float*)d_in[14];
    const float* Wc = (const float*)d_in[15];
    const float* gc = (const float*)d_in[16];
    const float* bc = (const float*)d_in[17];
    float* out = (float*)d_out;

    const size_t NBF = (size_t)BSZ * FDIM;   // 8388608
    const size_t NBH = (size_t)BSZ * HDIM;   // 4194304

    unsigned short* xb     = (unsigned short*)d_ws;
    unsigned short* masked = xb + NBF;
    unsigned short* Pb     = masked + NBF;
    unsigned short* hA     = Pb + NBF;
    unsigned short* hB     = hA + NBH;
    unsigned short* hC     = hB + NBH;
    unsigned short* cmpl   = hC + NBH;            // bf16 B x 256
    unsigned short* W1t    = cmpl + NBF;          // 65536
    unsigned short* W2t    = W1t + 65536;         // 32768
    unsigned short* W3t    = W2t + 32768;         // 5*32768
    unsigned short* W4t    = W3t + 163840;        // 5*32768
    unsigned short* Wct    = W4t + 163840;        // 5*16384
    float* stats = (float*)(Wct + 81920);         // 26 slots * 512
    float* ent   = stats + 26 * 512;              // 256 slots * 32 (128B spread)

    hipMemsetAsync(stats, 0, (26 * 512 + 256 * 32) * sizeof(float), stream);

    prep_w<<<dim3(17, 8), 256, 0, stream>>>(W1, W2, W3, W4, Wc, W1t, W2t, W3t, W4t, Wct);
    colstats<<<512, 256, 0, stream>>>(x, stats);
    norm_x<<<BSZ, 256, 0, stream>>>(x, stats, enc_g, enc_b, xb, out);

    const dim3 ggrid(2, 256);            // (N/128, B/128)
    const int NGLU = (BSZ * HDIM) / (256 * 4);   // 4096

    for (int ni = 0; ni < 5; ++ni) {
        float* s1 = stats + (size_t)(1 + ni * 5 + 0) * 512;
        float* s2 = stats + (size_t)(1 + ni * 5 + 1) * 512;
        float* s3 = stats + (size_t)(1 + ni * 5 + 2) * 512;
        float* s4 = stats + (size_t)(1 + ni * 5 + 3) * 512;
        float* s5 = stats + (size_t)(1 + ni * 5 + 4) * 512;

        const unsigned short* in1 = (ni == 0) ? xb : masked;

        gemm_bf16<<<ggrid, 256, 0, stream>>>(in1, 256, 0, W1t, 256, Pb, s1);
        norm_glu<false><<<NGLU, 256, 0, stream>>>(Pb, s1, g1, b1, nullptr, hA);

        gemm_bf16<<<ggrid, 256, 0, stream>>>(hA, 128, 0, W2t, 128, Pb, s2);
        norm_glu<true><<<NGLU, 256, 0, stream>>>(Pb, s2, g2, b2, hA, hB);

        gemm_bf16<<<ggrid, 256, 0, stream>>>(hB, 128, 0, W3t + (size_t)ni * 32768, 128, Pb, s3);
        norm_glu<true><<<NGLU, 256, 0, stream>>>(Pb, s3, g3 + ni * 256, b3 + ni * 256, hB, hC);

        gemm_bf16<<<ggrid, 256, 0, stream>>>(hC, 128, 0, W4t + (size_t)ni * 32768, 128, Pb, s4);
        norm_glu<true><<<NGLU, 256, 0, stream>>>(Pb, s4, g4 + ni * 256, b4 + ni * 256, hC, hA);

        gemm_bf16<<<ggrid, 256, 0, stream>>>(hA, 128, 64, Wct + (size_t)ni * 16384, 64, Pb, s5);
        if (ni == 0)
            coef_mask<true><<<BSZ / 4, 256, 0, stream>>>(Pb, s5, gc, bc, xb, cmpl, masked, ent);
        else
            coef_mask<false><<<BSZ / 4, 256, 0, stream>>>(Pb, s5, gc + ni * 256, bc + ni * 256,
                                                          xb, cmpl, masked, ent);
    }

    write_ent<<<1, 64, 0, stream>>>(ent, out + (size_t)BSZ * OUTD);
}

// Round 5
// 701.302 us; speedup vs baseline: 5.1093x; 1.1837x over previous
//
#include <hip/hip_runtime.h>
#include <math.h>

#define BSZ   32768
#define FDIM  256
#define HDIM  128
#define OUTD  64
#define SQRT_HALF 0.70710678118654752f
#define BN_EPS 1e-5f
#define SM_EPS 1e-5f
#define INV_B (1.0f / 32768.0f)

typedef __attribute__((ext_vector_type(8))) short bf16x8;
typedef __attribute__((ext_vector_type(4))) float f32x4;

__device__ __forceinline__ float b2f(unsigned short u) {
    return __uint_as_float(((unsigned int)u) << 16);
}
__device__ __forceinline__ unsigned short f2b(float f) {
    unsigned int u = __float_as_uint(f);
    u += 0x7fff + ((u >> 16) & 1);   // RNE
    return (unsigned short)(u >> 16);
}

// async global->LDS, 16B per lane; LDS dest = wave-uniform base + lane*16
__device__ __forceinline__ void async16(const void* g, void* l) {
    __builtin_amdgcn_global_load_lds(
        (const __attribute__((address_space(1))) void*)(uintptr_t)g,
        (__attribute__((address_space(3))) void*)(unsigned int)(uintptr_t)l,
        16, 0, 0);
}

__device__ inline float waveMaxAll(float v) {
#pragma unroll
    for (int m = 32; m > 0; m >>= 1) v = fmaxf(v, __shfl_xor(v, m, 64));
    return v;
}
__device__ inline float waveSumAll(float v) {
#pragma unroll
    for (int m = 32; m > 0; m >>= 1) v += __shfl_xor(v, m, 64);
    return v;
}

// XCD-pair swizzle: blocks b and b+8 (same XCD, round-robin %8) get the two
// column tiles of the same 128-row stripe -> A/P reads dedupe in that XCD's L2.
__device__ __forceinline__ void swizzle(int b, int& row0, int& col0, int& bx) {
    const int by = ((b >> 4) << 3) | (b & 7);
    bx = (b >> 3) & 1;
    row0 = by * 128;
    col0 = bx * 128;
}

// ---------------- weight prep: fp32 (K x 256) -> bf16 transposed (256 x K) ----------------
__global__ __launch_bounds__(256) void prep_w(
    const float* __restrict__ W1, const float* __restrict__ W2,
    const float* __restrict__ W3, const float* __restrict__ W4,
    const float* __restrict__ Wc,
    unsigned short* __restrict__ W1t, unsigned short* __restrict__ W2t,
    unsigned short* __restrict__ W3t, unsigned short* __restrict__ W4t,
    unsigned short* __restrict__ Wct)
{
    const int m = blockIdx.x, kz = blockIdx.y, n = threadIdx.x;
    const float* src; unsigned short* dst; int K;
    if (m == 0)      { src = W1;                        dst = W1t;               K = 256; }
    else if (m == 1) { src = W2;                        dst = W2t;               K = 128; }
    else if (m < 7)  { int i = m - 2;  src = W3 + (size_t)i * 128 * 256; dst = W3t + (size_t)i * 32768; K = 128; }
    else if (m < 12) { int i = m - 7;  src = W4 + (size_t)i * 128 * 256; dst = W4t + (size_t)i * 32768; K = 128; }
    else             { int i = m - 12; src = Wc + (size_t)i * 64 * 256;  dst = Wct + (size_t)i * 16384; K = 64; }
    const int k0 = kz * 32;
    if (k0 >= K) return;
    for (int k = k0; k < k0 + 32; ++k)
        dst[(size_t)n * K + k] = f2b(src[(size_t)k * 256 + n]);
}

// ---------------- column stats for x (B x 256) ----------------
__global__ __launch_bounds__(256) void colstats(const float* __restrict__ X,
                                                float* __restrict__ stats) {
    const int c = threadIdx.x;
    float s = 0.f, q = 0.f;
    for (int r = blockIdx.x; r < BSZ; r += gridDim.x) {
        float v = X[(size_t)r * FDIM + c];
        s += v; q += v * v;
    }
    atomicAdd(&stats[c], s);
    atomicAdd(&stats[FDIM + c], q);
}

// ---------------- normalize x -> xb(bf16), out = 5*relu(x_bn[:, :64]) ----------------
__global__ __launch_bounds__(256) void norm_x(const float* __restrict__ x,
                                              const float* __restrict__ stats,
                                              const float* __restrict__ g,
                                              const float* __restrict__ b,
                                              unsigned short* __restrict__ xb,
                                              float* __restrict__ out) {
    const int idx = blockIdx.x * 256 + threadIdx.x;
    const int row = idx >> 8, c = idx & 255;
    float mean = stats[c] * INV_B;
    float var  = stats[FDIM + c] * INV_B - mean * mean;
    float sc   = g[c] * rsqrtf(var + BN_EPS);
    float sh   = b[c] - mean * sc;
    float n = x[idx] * sc + sh;
    xb[idx] = f2b(n);
    if (c < OUTD) out[(size_t)row * OUTD + c] = 5.0f * fmaxf(n, 0.0f);
}

// ---------------- plain bf16 MFMA GEMM (stage 1), fused column stats ----------------
__global__ __launch_bounds__(256) void gemm_bf16(
    const unsigned short* __restrict__ A,
    const unsigned short* __restrict__ Wt, int K,
    unsigned short* __restrict__ P,
    float* __restrict__ stats)
{
    __shared__ short As[128 * 32];
    __shared__ short Bs[128 * 32];
    __shared__ float redS[2][128];
    __shared__ float redQ[2][128];

    const int tid  = threadIdx.x;
    const int wave = tid >> 6;
    const int lane = tid & 63;
    const int waveM = wave >> 1, waveN = wave & 1;
    int row0, col0, bx;
    swizzle(blockIdx.x, row0, col0, bx);

    const int sr = lane >> 2;
    const int sc = (lane & 3) * 8;

    f32x4 acc[4][4];
#pragma unroll
    for (int i = 0; i < 4; ++i)
#pragma unroll
        for (int j = 0; j < 4; ++j)
            acc[i][j] = (f32x4){0.f, 0.f, 0.f, 0.f};

    const int fm = lane & 15;
    const int fq = (lane >> 4) * 8;

    for (int k0 = 0; k0 < K; k0 += 32) {
#pragma unroll
        for (int t = 0; t < 2; ++t) {
            const int rr = (wave * 2 + t) * 16 + sr;
            async16(A  + (size_t)(row0 + rr) * K + k0 + sc,
                    (void*)(As + (wave * 2 + t) * 512 + lane * 8));
            async16(Wt + (size_t)(col0 + rr) * K + k0 + sc,
                    (void*)(Bs + (wave * 2 + t) * 512 + lane * 8));
        }
        __syncthreads();

        bf16x8 af[4], bfr[4];
#pragma unroll
        for (int i = 0; i < 4; ++i)
            af[i] = *(const bf16x8*)(As + (waveM * 64 + i * 16 + fm) * 32 + fq);
#pragma unroll
        for (int j = 0; j < 4; ++j)
            bfr[j] = *(const bf16x8*)(Bs + (waveN * 64 + j * 16 + fm) * 32 + fq);
#pragma unroll
        for (int i = 0; i < 4; ++i)
#pragma unroll
            for (int j = 0; j < 4; ++j)
                acc[i][j] = __builtin_amdgcn_mfma_f32_16x16x32_bf16(af[i], bfr[j], acc[i][j], 0, 0, 0);
        __syncthreads();
    }

    const int orow = row0 + waveM * 64 + (lane >> 4) * 4;
    const int ocol = col0 + waveN * 64 + fm;
#pragma unroll
    for (int i = 0; i < 4; ++i)
#pragma unroll
        for (int j = 0; j < 4; ++j)
#pragma unroll
            for (int r = 0; r < 4; ++r)
                P[(size_t)(orow + i * 16 + r) * 256 + (ocol + j * 16)] = f2b(acc[i][j][r]);

#pragma unroll
    for (int j = 0; j < 4; ++j) {
        float s = 0.f, q = 0.f;
#pragma unroll
        for (int i = 0; i < 4; ++i)
#pragma unroll
            for (int r = 0; r < 4; ++r) {
                float v = acc[i][j][r];
                s += v; q += v * v;
            }
        s += __shfl_xor(s, 16, 64); s += __shfl_xor(s, 32, 64);
        q += __shfl_xor(q, 16, 64); q += __shfl_xor(q, 32, 64);
        if (lane < 16) {
            redS[waveM][waveN * 64 + j * 16 + lane] = s;
            redQ[waveM][waveN * 64 + j * 16 + lane] = q;
        }
    }
    __syncthreads();
    if (tid < 128) {
        atomicAdd(&stats[col0 + tid], redS[0][tid] + redS[1][tid]);
    } else {
        const int t = tid - 128;
        atomicAdd(&stats[256 + col0 + t], redQ[0][t] + redQ[1][t]);
    }
}

// ---------------- fused BN+GLU(+res) prologue GEMM ----------------
// A[row][k] = glu(BN(Pprev[row][colOff+k], Pprev[row][colOff+k+128])) (+res)*sqrt(1/2)
// computed on the fly into LDS; col-block 0 also writes h to hOut (lda 128).
template <bool RES, bool WRITE_H>
__global__ __launch_bounds__(256) void gemm_glu(
    const unsigned short* __restrict__ Pprev,
    const float* __restrict__ pstats,
    const float* __restrict__ pg,
    const float* __restrict__ pb,
    const unsigned short* __restrict__ res,   // pre-offset, lda 128
    int colOff,
    const unsigned short* __restrict__ Wt, int K,
    unsigned short* __restrict__ Pout,
    float* __restrict__ stats,
    unsigned short* __restrict__ hOut)
{
    __shared__ short As[128 * 32];
    __shared__ short Bs[128 * 32];
    __shared__ float redS[2][128];
    __shared__ float redQ[2][128];
    __shared__ float tScA[128], tShA[128], tScG[128], tShG[128];

    const int tid  = threadIdx.x;
    const int wave = tid >> 6;
    const int lane = tid & 63;
    const int waveM = wave >> 1, waveN = wave & 1;
    int row0, col0, bx;
    swizzle(blockIdx.x, row0, col0, bx);

    // per-column BN affine tables
    if (tid < K) {
        const int ch = colOff + tid;
        float ma = pstats[ch] * INV_B;
        float va = pstats[256 + ch] * INV_B - ma * ma;
        float sA = pg[ch] * rsqrtf(va + BN_EPS);
        tScA[tid] = sA; tShA[tid] = pb[ch] - ma * sA;
        const int cg = ch + 128;
        float mg = pstats[cg] * INV_B;
        float vg = pstats[256 + cg] * INV_B - mg * mg;
        float sG = pg[cg] * rsqrtf(vg + BN_EPS);
        tScG[tid] = sG; tShG[tid] = pb[cg] - mg * sG;
    }
    __syncthreads();

    const int sr = lane >> 2;
    const int sc = (lane & 3) * 8;

    f32x4 acc[4][4];
#pragma unroll
    for (int i = 0; i < 4; ++i)
#pragma unroll
        for (int j = 0; j < 4; ++j)
            acc[i][j] = (f32x4){0.f, 0.f, 0.f, 0.f};

    const int fm = lane & 15;
    const int fq = (lane >> 4) * 8;

    for (int k0 = 0; k0 < K; k0 += 32) {
#pragma unroll
        for (int t = 0; t < 2; ++t) {
            const int rr = (wave * 2 + t) * 16 + sr;
            const size_t grow = (size_t)(row0 + rr);
            const int kk = k0 + sc;

            bf16x8 lo = *(const bf16x8*)(Pprev + grow * 256 + colOff + kk);
            bf16x8 hi = *(const bf16x8*)(Pprev + grow * 256 + colOff + kk + 128);
            bf16x8 rv;
            if (RES) rv = *(const bf16x8*)(res + grow * 128 + kk);

            float4 a0 = *(const float4*)&tScA[kk], a1 = *(const float4*)&tScA[kk + 4];
            float4 h0 = *(const float4*)&tShA[kk], h1 = *(const float4*)&tShA[kk + 4];
            float4 g0 = *(const float4*)&tScG[kk], g1 = *(const float4*)&tScG[kk + 4];
            float4 s0 = *(const float4*)&tShG[kk], s1 = *(const float4*)&tShG[kk + 4];
            float scA[8] = {a0.x, a0.y, a0.z, a0.w, a1.x, a1.y, a1.z, a1.w};
            float shA[8] = {h0.x, h0.y, h0.z, h0.w, h1.x, h1.y, h1.z, h1.w};
            float scG[8] = {g0.x, g0.y, g0.z, g0.w, g1.x, g1.y, g1.z, g1.w};
            float shG[8] = {s0.x, s0.y, s0.z, s0.w, s1.x, s1.y, s1.z, s1.w};

            bf16x8 o8;
#pragma unroll
            for (int e = 0; e < 8; ++e) {
                float na = b2f((unsigned short)lo[e]) * scA[e] + shA[e];
                float ng = b2f((unsigned short)hi[e]) * scG[e] + shG[e];
                float v = na * (1.0f / (1.0f + __expf(-ng)));
                if (RES) v = (v + b2f((unsigned short)rv[e])) * SQRT_HALF;
                o8[e] = (short)f2b(v);
            }
            *(bf16x8*)(As + (wave * 2 + t) * 512 + lane * 8) = o8;
            if (WRITE_H && bx == 0)
                *(bf16x8*)(hOut + grow * 128 + kk) = o8;

            async16(Wt + (size_t)(col0 + rr) * K + k0 + sc,
                    (void*)(Bs + (wave * 2 + t) * 512 + lane * 8));
        }
        __syncthreads();

        bf16x8 af[4], bfr[4];
#pragma unroll
        for (int i = 0; i < 4; ++i)
            af[i] = *(const bf16x8*)(As + (waveM * 64 + i * 16 + fm) * 32 + fq);
#pragma unroll
        for (int j = 0; j < 4; ++j)
            bfr[j] = *(const bf16x8*)(Bs + (waveN * 64 + j * 16 + fm) * 32 + fq);
#pragma unroll
        for (int i = 0; i < 4; ++i)
#pragma unroll
            for (int j = 0; j < 4; ++j)
                acc[i][j] = __builtin_amdgcn_mfma_f32_16x16x32_bf16(af[i], bfr[j], acc[i][j], 0, 0, 0);
        __syncthreads();
    }

    const int orow = row0 + waveM * 64 + (lane >> 4) * 4;
    const int ocol = col0 + waveN * 64 + fm;
#pragma unroll
    for (int i = 0; i < 4; ++i)
#pragma unroll
        for (int j = 0; j < 4; ++j)
#pragma unroll
            for (int r = 0; r < 4; ++r)
                Pout[(size_t)(orow + i * 16 + r) * 256 + (ocol + j * 16)] = f2b(acc[i][j][r]);

#pragma unroll
    for (int j = 0; j < 4; ++j) {
        float s = 0.f, q = 0.f;
#pragma unroll
        for (int i = 0; i < 4; ++i)
#pragma unroll
            for (int r = 0; r < 4; ++r) {
                float v = acc[i][j][r];
                s += v; q += v * v;
            }
        s += __shfl_xor(s, 16, 64); s += __shfl_xor(s, 32, 64);
        q += __shfl_xor(q, 16, 64); q += __shfl_xor(q, 32, 64);
        if (lane < 16) {
            redS[waveM][waveN * 64 + j * 16 + lane] = s;
            redQ[waveM][waveN * 64 + j * 16 + lane] = q;
        }
    }
    __syncthreads();
    if (tid < 128) {
        atomicAdd(&stats[col0 + tid], redS[0][tid] + redS[1][tid]);
    } else {
        const int t = tid - 128;
        atomicAdd(&stats[256 + col0 + t], redQ[0][t] + redQ[1][t]);
    }
}

// ---------------- coef BN -> softmax -> mask/compl/entropy ----------------
template <bool FIRST>
__global__ __launch_bounds__(256) void coef_mask(const unsigned short* __restrict__ Pc,
                                                 const float* __restrict__ stats,
                                                 const float* __restrict__ gc,
                                                 const float* __restrict__ bc,
                                                 const unsigned short* __restrict__ xb,
                                                 unsigned short* __restrict__ cmpl,
                                                 unsigned short* __restrict__ masked,
                                                 float* __restrict__ ent) {
    const int w    = threadIdx.x >> 6;
    const int lane = threadIdx.x & 63;
    const int row  = blockIdx.x * 4 + w;
    const int c    = lane << 2;
    __shared__ float went[4];

    float4 sv = *(const float4*)&stats[c];
    float4 qv = *(const float4*)&stats[256 + c];
    float4 gv = *(const float4*)&gc[c];
    float4 bv = *(const float4*)&bc[c];
    const float* svv = (const float*)&sv; const float* qvv = (const float*)&qv;
    const float* gvv = (const float*)&gv; const float* bvv = (const float*)&bv;

    float scl[4], shf[4];
#pragma unroll
    for (int e = 0; e < 4; ++e) {
        float mean = svv[e] * INV_B, var = qvv[e] * INV_B - mean * mean;
        scl[e] = gvv[e] * rsqrtf(var + BN_EPS);
        shf[e] = bvv[e] - mean * scl[e];
    }

    const size_t idx = (size_t)row * 256 + c;
    ushort4 pu = *(const ushort4*)(Pc + idx);
    ushort4 xu = *(const ushort4*)(xb + idx);
    const unsigned short* puv = (const unsigned short*)&pu;
    const unsigned short* xuv = (const unsigned short*)&xu;

    float cl[4] = {1.f, 1.f, 1.f, 1.f};
    if (!FIRST) {
        ushort4 cu = *(const ushort4*)(cmpl + idx);
        const unsigned short* cuv = (const unsigned short*)&cu;
#pragma unroll
        for (int e = 0; e < 4; ++e) cl[e] = b2f(cuv[e]);
    }

    float l[4];
#pragma unroll
    for (int e = 0; e < 4; ++e) l[e] = (b2f(puv[e]) * scl[e] + shf[e]) * cl[e];

    float mx = waveMaxAll(fmaxf(fmaxf(l[0], l[1]), fmaxf(l[2], l[3])));
    float e0 = __expf(l[0] - mx), e1 = __expf(l[1] - mx),
          e2 = __expf(l[2] - mx), e3 = __expf(l[3] - mx);
    float inv = 1.0f / waveSumAll(e0 + e1 + e2 + e3);

    float m[4] = {e0 * inv, e1 * inv, e2 * inv, e3 * inv};

    float et = -m[0] * __logf(m[0] + SM_EPS) - m[1] * __logf(m[1] + SM_EPS)
             - m[2] * __logf(m[2] + SM_EPS) - m[3] * __logf(m[3] + SM_EPS);
    et = waveSumAll(et);
    if (lane == 0) went[w] = et;
    __syncthreads();
    if (threadIdx.x == 0) {
        float v = went[0] + went[1] + went[2] + went[3];
        atomicAdd(&ent[(blockIdx.x & 255) << 5], v * (INV_B * 0.2f));
    }

    ushort4 co, mo;
    unsigned short* cop = (unsigned short*)&co;
    unsigned short* mop = (unsigned short*)&mo;
#pragma unroll
    for (int e = 0; e < 4; ++e) {
        cop[e] = f2b(cl[e] * (1.5f - m[e]));
        mop[e] = f2b(m[e] * b2f(xuv[e]));
    }
    *(ushort4*)&cmpl[idx]   = co;
    *(ushort4*)&masked[idx] = mo;
}

__global__ __launch_bounds__(64) void write_ent(const float* __restrict__ ent,
                                                float* __restrict__ dst) {
    const int lane = threadIdx.x;
    float v = 0.f;
#pragma unroll
    for (int i = 0; i < 4; ++i) v += ent[(lane + 64 * i) << 5];
    v = waveSumAll(v);
    if (lane == 0) dst[0] = v;
}

// ---------------- host orchestration ----------------
extern "C" void kernel_launch(void* const* d_in, const int* in_sizes, int n_in,
                              void* d_out, int out_size, void* d_ws, size_t ws_size,
                              hipStream_t stream) {
    const float* x     = (const float*)d_in[0];
    const float* enc_g = (const float*)d_in[1];
    const float* enc_b = (const float*)d_in[2];
    const float* W1 = (const float*)d_in[3];
    const float* g1 = (const float*)d_in[4];
    const float* b1 = (const float*)d_in[5];
    const float* W2 = (const float*)d_in[6];
    const float* g2 = (const float*)d_in[7];
    const float* b2 = (const float*)d_in[8];
    const float* W3 = (const float*)d_in[9];
    const float* g3 = (const float*)d_in[10];
    const float* b3 = (const float*)d_in[11];
    const float* W4 = (const float*)d_in[12];
    const float* g4 = (const float*)d_in[13];
    const float* b4 = (const float*)d_in[14];
    const float* Wc = (const float*)d_in[15];
    const float* gc = (const float*)d_in[16];
    const float* bc = (const float*)d_in[17];
    float* out = (float*)d_out;

    const size_t NBF = (size_t)BSZ * FDIM;   // 8388608
    const size_t NBH = (size_t)BSZ * HDIM;   // 4194304

    unsigned short* xb     = (unsigned short*)d_ws;
    unsigned short* masked = xb + NBF;       // doubles as P ping buffer Pb2
    unsigned short* Pb1    = masked + NBF;
    unsigned short* h1     = Pb1 + NBF;
    unsigned short* h2     = h1 + NBH;
    unsigned short* h3     = h2 + NBH;
    unsigned short* cmpl   = h3 + NBH;
    unsigned short* W1t    = cmpl + NBF;          // 65536
    unsigned short* W2t    = W1t + 65536;         // 32768
    unsigned short* W3t    = W2t + 32768;         // 5*32768
    unsigned short* W4t    = W3t + 163840;        // 5*32768
    unsigned short* Wct    = W4t + 163840;        // 5*16384
    float* stats = (float*)(Wct + 81920);         // 26 slots * 512
    float* ent   = stats + 26 * 512;              // 256 slots * 32 (128B spread)

    unsigned short* Pb2 = masked;

    hipMemsetAsync(stats, 0, (26 * 512 + 256 * 32) * sizeof(float), stream);

    prep_w<<<dim3(17, 8), 256, 0, stream>>>(W1, W2, W3, W4, Wc, W1t, W2t, W3t, W4t, Wct);
    colstats<<<512, 256, 0, stream>>>(x, stats);
    norm_x<<<BSZ, 256, 0, stream>>>(x, stats, enc_g, enc_b, xb, out);

    for (int ni = 0; ni < 5; ++ni) {
        float* s1 = stats + (size_t)(1 + ni * 5 + 0) * 512;
        float* s2 = stats + (size_t)(1 + ni * 5 + 1) * 512;
        float* s3 = stats + (size_t)(1 + ni * 5 + 2) * 512;
        float* s4 = stats + (size_t)(1 + ni * 5 + 3) * 512;
        float* s5 = stats + (size_t)(1 + ni * 5 + 4) * 512;

        const unsigned short* in1 = (ni == 0) ? xb : masked;

        // s1: P1 = A @ W1 (A materialized)
        gemm_bf16<<<512, 256, 0, stream>>>(in1, W1t, 256, Pb1, s1);
        // s2: A = h1 = glu(P1);           P2 = h1 @ W2   (writes h1)
        gemm_glu<false, true><<<512, 256, 0, stream>>>(
            Pb1, s1, g1, b1, nullptr, 0, W2t, 128, Pb2, s2, h1);
        // s3: A = h2 = (glu(P2)+h1)*c;    P3 = h2 @ W3   (writes h2)
        gemm_glu<true, true><<<512, 256, 0, stream>>>(
            Pb2, s2, g2, b2, h1, 0, W3t + (size_t)ni * 32768, 128, Pb1, s3, h2);
        // s4: A = h3 = (glu(P3)+h2)*c;    P4 = h3 @ W4   (writes h3)
        gemm_glu<true, true><<<512, 256, 0, stream>>>(
            Pb1, s3, g3 + ni * 256, b3 + ni * 256, h2, 0,
            W4t + (size_t)ni * 32768, 128, Pb2, s4, h3);
        // s5: A = h4[:,64:] = (glu(P4)+h3)[:,64:]*c;  Pc = A @ Wc
        gemm_glu<true, false><<<512, 256, 0, stream>>>(
            Pb2, s4, g4 + ni * 256, b4 + ni * 256, h3 + 64, 64,
            Wct + (size_t)ni * 16384, 64, Pb1, s5, nullptr);

        if (ni == 0)
            coef_mask<true><<<BSZ / 4, 256, 0, stream>>>(Pb1, s5, gc, bc, xb, cmpl, masked, ent);
        else
            coef_mask<false><<<BSZ / 4, 256, 0, stream>>>(Pb1, s5, gc + ni * 256, bc + ni * 256,
                                                          xb, cmpl, masked, ent);
    }

    write_ent<<<1, 64, 0, stream>>>(ent, out + (size_t)BSZ * OUTD);
}